// Round 5
// baseline (299.033 us; speedup 1.0000x reference)
//
#include <hip/hip_runtime.h>

#define N_ 16
#define C_ 128
#define H_ 56
#define W_ 56
#define HW_ 3136

typedef __bf16 bf16x8 __attribute__((ext_vector_type(8)));
typedef __bf16 bf16x2 __attribute__((ext_vector_type(2)));
typedef float f32x4 __attribute__((ext_vector_type(4)));

#define XT_PER_N 401408   // 128*3136 (transposed x, bf16, [c][w][h])
#define T2_PLANE 3472     // 62*56 per channel (h-padded t2, bf16)
#define T2_PER_N 444416   // 128*3472
#define S_PER_N 114688    // 128*896
#define T10_PER_N 401408  // 128*3136

// workspace byte offsets (proven layout)
#define WS_T10_OFF   3670016u
#define WS_T3_OFF    12845056u
#define WS_T2PB_OFF  20185088u
#define WS_W2B_OFF   34406400u  // 98304 B, end 34504704

// ---------------------------------------------------------------------------
// w2b[co][j*128+ci] = bf16(w2[co][ci*3+j])  — A-operand pack for k1 MFMA
// ---------------------------------------------------------------------------
__global__ __launch_bounds__(256) void w2b_prep(const float* __restrict__ w2,
                                                __bf16* __restrict__ w2b) {
    int idx = blockIdx.x * 256 + threadIdx.x;  // < 49152
    int co = idx / 384, kk = idx - co * 384;
    int j = kk >> 7, ci = kk & 127;
    w2b[idx] = (__bf16)w2[co * 384 + ci * 3 + j];
}

// ---------------------------------------------------------------------------
// P1: xT[n][c][w][h] = x[n][c][h][w]  (bf16, unpadded 56x56 planes)
// ---------------------------------------------------------------------------
__global__ __launch_bounds__(256) void p1_transpose(const float* __restrict__ x,
                                                    __bf16* __restrict__ xT) {
    int c = blockIdx.x, n = blockIdx.y;
    __shared__ float xs[56 * 57];
    int tid = threadIdx.x;
    const float* xp = x + (size_t)(n * C_ + c) * HW_;
    for (int i = tid; i < HW_; i += 256) {
        int h = i / 56, w = i - 56 * h;
        xs[w * 57 + h] = xp[i];
    }
    __syncthreads();
    __bf16* op = xT + (size_t)(n * C_ + c) * HW_;
    for (int i = tid; i < 1568; i += 256) {
        int j = 2 * i;
        int wp = j / 56, h = j - 56 * wp;
        bf16x2 pr = {(__bf16)xs[wp * 57 + h], (__bf16)xs[wp * 57 + h + 1]};
        *(bf16x2*)&op[j] = pr;
    }
}

// ---------------------------------------------------------------------------
// K1 (MFMA): t2[co][w] = sum_{kk=(j,ci)} w2b[co][kk] * x[ci][h][w+j-1]
// A-frags read DIRECT from global (w2b is 96KB, L2-hot, shared by all blocks)
// -> only one barrier (after Bs stage) before the K loop.
// ---------------------------------------------------------------------------
__global__ __launch_bounds__(256) void k1_mfma(const float* __restrict__ x,
                                               const __bf16* __restrict__ w2b,
                                               __bf16* __restrict__ t2pb) {
    int h = blockIdx.x, n = blockIdx.y;
    __shared__ __align__(16) __bf16 Bs[66 * 136];  // 17952 B
    __shared__ __align__(16) float kbuf[32 * 65];  // 8320 B (store transpose)
    int tid = threadIdx.x;
    int wv = tid >> 6, lane = tid & 63;
    int lm = lane & 15, lq = lane >> 4;
    int wi = wv >> 1, wj = wv & 1;

    // stage Bs once: Bs[wp*136 + ci] = x[ci][h][wp-1] (0 outside [0,56))
    const float* xn = x + (size_t)n * C_ * HW_ + h * 56;
    for (int i = tid; i < 66 * 128; i += 256) {
        int ci = i / 66, wp = i - 66 * ci;
        int wx = wp - 1;
        float v = (wx >= 0 && wx < 56) ? xn[ci * HW_ + wx] : 0.f;
        Bs[wp * 136 + ci] = (__bf16)v;
    }
    __syncthreads();

    f32x4 acc[4][2];
    f32x4 zero4 = {0.f, 0.f, 0.f, 0.f};
#pragma unroll
    for (int i = 0; i < 4; i++)
#pragma unroll
        for (int j = 0; j < 2; j++) acc[i][j] = zero4;

#pragma unroll 4
    for (int ks = 0; ks < 12; ks++) {
        int j = ks >> 2;             // tap 0..2
        int cbase = (ks & 3) * 32;   // ci block base
        bf16x8 av[4], bv[2];
#pragma unroll
        for (int i = 0; i < 4; i++)
            av[i] = *(const bf16x8*)(w2b + (wi * 64 + i * 16 + lm) * 384 + ks * 32 + lq * 8);
#pragma unroll
        for (int jt = 0; jt < 2; jt++) {
            int row = wj * 32 + jt * 16 + lm + j;
            bv[jt] = *(const bf16x8*)&Bs[row * 136 + cbase + lq * 8];
        }
#pragma unroll
        for (int i = 0; i < 4; i++)
#pragma unroll
            for (int jt = 0; jt < 2; jt++)
                acc[i][jt] = __builtin_amdgcn_mfma_f32_16x16x32_bf16(av[i], bv[jt], acc[i][jt], 0, 0, 0);
    }

    // store via LDS transpose: 4 chunks of 32 co-rows x 64 w
    __bf16* t2n = t2pb + (size_t)n * T2_PER_N;
#pragma unroll 1
    for (int i = 0; i < 4; i++) {
        __syncthreads();
#pragma unroll
        for (int jt = 0; jt < 2; jt++)
#pragma unroll
            for (int r = 0; r < 4; r++)
                kbuf[(wi * 16 + lq * 4 + r) * 65 + wj * 32 + jt * 16 + lm] = acc[i][jt][r];
        __syncthreads();
        int row = tid >> 3, seg = tid & 7;
        if (seg < 7) {
            int co = (row < 16) ? (i * 16 + row) : (64 + i * 16 + (row - 16));
            const float* src = &kbuf[row * 65 + seg * 8];
            bf16x8 o8;
#pragma unroll
            for (int d = 0; d < 8; d++) o8[d] = (__bf16)src[d];
            *(bf16x8*)(t2n + (size_t)co * T2_PLANE + (h + 3) * 56 + seg * 8) = o8;
        }
    }
}

// ---------------------------------------------------------------------------
// K2 (LDS-FREE): t3[n,k,a,b] += (1/56) sum_j xT[a][j+(2k-6)*56] * xT[b][j]
// over the valid linear range j in [w_lo*56, w_hi*56). Both MFMA operands are
// row x contiguous-K -> each lane loads its fragments directly from global
// (16B aligned). Zero barriers; compiler pipelines loads across MFMA.
// Grid (8, 7, N_) = 896 blocks; K chunks of 64 strided by 8 across blocks.
// ---------------------------------------------------------------------------
__global__ __launch_bounds__(256) void k2_mfma(const __bf16* __restrict__ xT,
                                               float* __restrict__ t3) {
    int hc = blockIdx.x, k = blockIdx.y, n = blockIdx.z;
    int w_lo = 6 - 2 * k; if (w_lo < 0) w_lo = 0;
    int w_hi = 62 - 2 * k; if (w_hi > 56) w_hi = 56;
    int jlo = w_lo * 56;
    int L = (w_hi - w_lo) * 56;           // 2800..3136, multiple of 56
    int T = (L + 63) >> 6;                // chunks of 64
    int shiftA = (2 * k - 6) * 56;

    int tid = threadIdx.x;
    int wv = tid >> 6, lane = tid & 63;
    int lm = lane & 15, lq = lane >> 4;
    int wi = wv >> 1, wj = wv & 1;

    f32x4 acc[4][4];
    f32x4 zero4 = {0.f, 0.f, 0.f, 0.f};
#pragma unroll
    for (int i = 0; i < 4; i++)
#pragma unroll
        for (int j = 0; j < 4; j++) acc[i][j] = zero4;

    const __bf16* xTn = xT + (size_t)n * XT_PER_N;
    __bf16 bz = (__bf16)0.f;
    bf16x8 vzero = {bz, bz, bz, bz, bz, bz, bz, bz};

    const __bf16* Arow[4];
    const __bf16* Brow[4];
#pragma unroll
    for (int i = 0; i < 4; i++)
        Arow[i] = xTn + (size_t)(wi * 64 + i * 16 + lm) * HW_ + jlo + shiftA + lq * 8;
#pragma unroll
    for (int j = 0; j < 4; j++)
        Brow[j] = xTn + (size_t)(wj * 64 + j * 16 + lm) * HW_ + jlo + lq * 8;

    for (int c = hc; c < T; c += 8) {
        int base = c * 64;
#pragma unroll
        for (int kb = 0; kb < 2; kb++) {
            int off = base + kb * 32;
            bool val = (off + lq * 8 + 8 <= L);  // octet-granular tail (L mult of 8)
            bf16x8 av[4], bv[4];
#pragma unroll
            for (int i = 0; i < 4; i++)
                av[i] = val ? *(const bf16x8*)(Arow[i] + off) : vzero;
#pragma unroll
            for (int j = 0; j < 4; j++)
                bv[j] = val ? *(const bf16x8*)(Brow[j] + off) : vzero;
#pragma unroll
            for (int i = 0; i < 4; i++)
#pragma unroll
                for (int j = 0; j < 4; j++)
                    acc[i][j] = __builtin_amdgcn_mfma_f32_16x16x32_bf16(av[i], bv[j], acc[i][j], 0, 0, 0);
        }
    }

    float* t3p = t3 + (size_t)(n * 7 + k) * (C_ * C_);
    const float inv56 = 1.0f / 56.0f;
#pragma unroll
    for (int i = 0; i < 4; i++)
#pragma unroll
        for (int j = 0; j < 4; j++)
#pragma unroll
            for (int r = 0; r < 4; r++) {
                int a = wi * 64 + i * 16 + lq * 4 + r;
                int b = wj * 64 + j * 16 + lm;
                atomicAdd(&t3p[a * C_ + b], acc[i][j][r] * inv56);
            }
}

// ---------------------------------------------------------------------------
// s-prep: s[n][b][ak] = bf16( t3[n][k][a][b] * p6w[a][k] * p9w[k][b] / sqrt(896) )
// ---------------------------------------------------------------------------
__global__ __launch_bounds__(256) void sprep(const float* __restrict__ t3,
                                             const float* __restrict__ p6w,
                                             const float* __restrict__ p9w,
                                             __bf16* __restrict__ s) {
    int idx = blockIdx.x * 256 + threadIdx.x;  // < 16*128*896
    int n = idx / S_PER_N;
    int rem = idx - n * S_PER_N;
    int b = rem / 896;
    int ak = rem - b * 896;
    int a = ak / 7, k = ak - 7 * a;
    const float rs = 0.03340766f;  // 1/sqrt(896)
    float v = t3[((size_t)(n * 7 + k) * C_ + a) * C_ + b] * p6w[a * 7 + k] *
              p9w[k * C_ + b] * rs;
    s[idx] = (__bf16)v;
}

// ---------------------------------------------------------------------------
// K3: t10[n][b][hw] = sum_ak s[b][ak] * t2pb_lin[a*3472 + hw + 56k]
// A (s, K-major) read DIRECT from global; Bs double-buffered (1 barrier/chunk).
// Tile 128(b) x 64(hw), grid (49, N_). bf16 output via LDS transpose.
// ---------------------------------------------------------------------------
__global__ __launch_bounds__(256) void k3_mfma(const __bf16* __restrict__ s,
                                               const __bf16* __restrict__ t2pb,
                                               __bf16* __restrict__ t10) {
    int tile = blockIdx.x;  // 0..48
    int n = blockIdx.y;
    int hw0 = tile * 64;
    __shared__ __align__(16) __bf16 Bs[2][64 * 72];  // 18432 B
    __shared__ __align__(16) float kbuf[32 * 65];    // 8320 B
    int tid = threadIdx.x;
    int wv = tid >> 6, lane = tid & 63;
    int lm = lane & 15, lq = lane >> 4;
    int wi = wv >> 1, wj = wv & 1;

    f32x4 acc[4][2];
    f32x4 zero4 = {0.f, 0.f, 0.f, 0.f};
#pragma unroll
    for (int i = 0; i < 4; i++)
#pragma unroll
        for (int j = 0; j < 2; j++) acc[i][j] = zero4;

    const __bf16* s_n = s + (size_t)n * S_PER_N;
    const __bf16* t2n = t2pb + (size_t)n * T2_PER_N;

    // Bs staging lambda-equivalent (manual): chunk kb -> buffer d
    int o = tid & 7;   // hw octet
    int p = tid >> 3;  // ak pair, [0,32)
    {
        // stage chunk 0 into Bs[0]
        int ak0 = 2 * p;
        int a0 = ak0 / 7, k0 = ak0 - 7 * a0;
        int ak1 = ak0 + 1;
        int a1 = ak1 / 7, k1 = ak1 - 7 * a1;
        int hwg = hw0 + 8 * o;
        bf16x8 v0 = *(const bf16x8*)(t2n + a0 * T2_PLANE + hwg + 56 * k0);
        bf16x8 v1 = *(const bf16x8*)(t2n + a1 * T2_PLANE + hwg + 56 * k1);
        int g = p >> 2;
        int off = (2 * p) & 7;
        int phys = ((g ^ o) << 3) + off;
#pragma unroll
        for (int j = 0; j < 8; j++) {
            int row = 8 * o + j;
            bf16x2 pr = {v0[j], v1[j]};
            *(bf16x2*)&Bs[0][row * 72 + phys] = pr;
        }
    }

    for (int kb = 0; kb < 14; kb++) {
        __syncthreads();  // Bs[kb&1] ready
        if (kb + 1 < 14) {
            int ak0 = (kb + 1) * 64 + 2 * p;
            int a0 = ak0 / 7, k0 = ak0 - 7 * a0;
            int ak1 = ak0 + 1;
            int a1 = ak1 / 7, k1 = ak1 - 7 * a1;
            int hwg = hw0 + 8 * o;
            bf16x8 v0 = *(const bf16x8*)(t2n + a0 * T2_PLANE + hwg + 56 * k0);
            bf16x8 v1 = *(const bf16x8*)(t2n + a1 * T2_PLANE + hwg + 56 * k1);
            int g = p >> 2;
            int off = (2 * p) & 7;
            int phys = ((g ^ o) << 3) + off;
#pragma unroll
            for (int j = 0; j < 8; j++) {
                int row = 8 * o + j;
                bf16x2 pr = {v0[j], v1[j]};
                *(bf16x2*)&Bs[(kb + 1) & 1][row * 72 + phys] = pr;
            }
        }
        const __bf16* Bcur = Bs[kb & 1];
#pragma unroll
        for (int kbi = 0; kbi < 2; kbi++) {
            bf16x8 av[4], bv[2];
#pragma unroll
            for (int i = 0; i < 4; i++)
                av[i] = *(const bf16x8*)(s_n + (wi * 64 + i * 16 + lm) * 896 + kb * 64 + kbi * 32 + lq * 8);
#pragma unroll
            for (int j = 0; j < 2; j++) {
                int row = wj * 32 + j * 16 + lm;
                int g = kbi * 4 + lq;
                int pg = g ^ (row >> 3);
                bv[j] = *(const bf16x8*)&Bcur[row * 72 + pg * 8];
            }
#pragma unroll
            for (int i = 0; i < 4; i++)
#pragma unroll
                for (int j = 0; j < 2; j++)
                    acc[i][j] = __builtin_amdgcn_mfma_f32_16x16x32_bf16(av[i], bv[j], acc[i][j], 0, 0, 0);
        }
    }

    __bf16* t10n = t10 + (size_t)n * T10_PER_N;
#pragma unroll 1
    for (int i = 0; i < 4; i++) {
        __syncthreads();
#pragma unroll
        for (int j = 0; j < 2; j++)
#pragma unroll
            for (int r = 0; r < 4; r++)
                kbuf[(wi * 16 + lq * 4 + r) * 65 + wj * 32 + j * 16 + lm] = acc[i][j][r];
        __syncthreads();
        int row = tid >> 3, seg = tid & 7;
        int b = (row < 16) ? (i * 16 + row) : (64 + i * 16 + (row - 16));
        const float* src = &kbuf[row * 65 + seg * 8];
        bf16x8 o8;
#pragma unroll
        for (int d = 0; d < 8; d++) o8[d] = (__bf16)src[d];
        *(bf16x8*)(t10n + (size_t)b * HW_ + hw0 + seg * 8) = o8;
    }
}

// ---------------------------------------------------------------------------
// D: out = t8 - t10 + t7, one block per (n,b) plane.
// ---------------------------------------------------------------------------
__global__ __launch_bounds__(256) void d_final(const float* __restrict__ x,
                                               const __bf16* __restrict__ t2pb,
                                               const __bf16* __restrict__ t10,
                                               const float* __restrict__ w7,
                                               const float* __restrict__ w8,
                                               float* __restrict__ out) {
    int b = blockIdx.x, n = blockIdx.y;
    __shared__ float xs[64 * 65];
    __shared__ float t2s[56 * 60];
    int tid = threadIdx.x;
    const float* xp = x + (size_t)(n * C_ + b) * HW_;
    for (int i = tid; i < 64 * 65; i += 256) {
        int hh = i / 65, ww = i - 65 * hh;
        int h = hh - 4, w = ww - 4;
        float v = (h >= 0 && h < 56 && w >= 0 && w < 56) ? xp[h * 56 + w] : 0.f;
        xs[i] = v;
    }
    const __bf16* t2p = t2pb + (size_t)(n * C_ + b) * T2_PLANE;
    for (int i = tid; i < 56 * 60; i += 256) {
        int h = i / 60, ww = i - 60 * h;
        int w = ww - 2;
        float v = (w >= 0 && w < 56) ? (float)t2p[(h + 3) * 56 + w] : 0.f;
        t2s[i] = v;
    }
    __syncthreads();

    int r = tid >> 2;
    if (r >= 56) return;
    int w0 = (tid & 3) * 14;

    float w7r[5], w8r[25];
#pragma unroll
    for (int q = 0; q < 5; q++) w7r[q] = w7[b * 5 + q];
#pragma unroll
    for (int q = 0; q < 25; q++) w8r[q] = w8[b * 25 + q];

    float acc[14];
    {
        float tw[18];
#pragma unroll
        for (int c = 0; c < 18; c++) tw[c] = t2s[r * 60 + w0 + c];
#pragma unroll
        for (int i = 0; i < 14; i++)
            acc[i] = tw[i] * w7r[0] + tw[i + 1] * w7r[1] + tw[i + 2] * w7r[2] +
                     tw[i + 3] * w7r[3] + tw[i + 4] * w7r[4];
    }
#pragma unroll
    for (int p = 0; p < 5; p++) {
        float xv[22];
        int base = (r + 2 * p) * 65 + w0;
#pragma unroll
        for (int c = 0; c < 22; c++) xv[c] = xs[base + c];
#pragma unroll
        for (int i = 0; i < 14; i++)
            acc[i] += xv[i] * w8r[p * 5 + 0] + xv[i + 2] * w8r[p * 5 + 1] +
                      xv[i + 4] * w8r[p * 5 + 2] + xv[i + 6] * w8r[p * 5 + 3] +
                      xv[i + 8] * w8r[p * 5 + 4];
    }
    const __bf16* t10r = t10 + (size_t)(n * C_ + b) * HW_ + r * 56 + w0;
    float* outr = out + (size_t)(n * C_ + b) * HW_ + r * 56 + w0;
#pragma unroll
    for (int i = 0; i < 14; i++) outr[i] = acc[i] - (float)t10r[i];
}

extern "C" void kernel_launch(void* const* d_in, const int* in_sizes, int n_in,
                              void* d_out, int out_size, void* d_ws, size_t ws_size,
                              hipStream_t stream) {
    const float* x = (const float*)d_in[0];
    const float* w2 = (const float*)d_in[1];
    const float* p6w = (const float*)d_in[2];
    const float* w7 = (const float*)d_in[3];
    const float* w8 = (const float*)d_in[4];
    const float* p9w = (const float*)d_in[5];
    float* outp = (float*)d_out;

    char* ws = (char*)d_ws;
    __bf16* xT = (__bf16*)ws;
    __bf16* s = (__bf16*)ws;                     // overlay (xT dead after k2)
    __bf16* t10 = (__bf16*)(ws + WS_T10_OFF);    // overlays xT tail + t3 head
    float* t3 = (float*)(ws + WS_T3_OFF);
    __bf16* t2pb = (__bf16*)(ws + WS_T2PB_OFF);
    __bf16* w2b = (__bf16*)(ws + WS_W2B_OFF);

    hipMemsetAsync(t2pb, 0, (size_t)N_ * C_ * T2_PLANE * sizeof(__bf16), stream);
    hipMemsetAsync(t3, 0, (size_t)N_ * 7 * C_ * C_ * sizeof(float), stream);

    w2b_prep<<<dim3(192), 256, 0, stream>>>(w2, w2b);
    p1_transpose<<<dim3(C_, N_), 256, 0, stream>>>(x, xT);
    k1_mfma<<<dim3(H_, N_), 256, 0, stream>>>(x, w2b, t2pb);
    k2_mfma<<<dim3(8, 7, N_), 256, 0, stream>>>(xT, t3);
    sprep<<<dim3((N_ * S_PER_N) / 256), 256, 0, stream>>>(t3, p6w, p9w, s);
    k3_mfma<<<dim3(49, N_), 256, 0, stream>>>(s, t2pb, t10);
    d_final<<<dim3(C_, N_), 256, 0, stream>>>(x, t2pb, t10, w7, w8, outp);
}

// Round 6
// 221.177 us; speedup vs baseline: 1.3520x; 1.3520x over previous
//
#include <hip/hip_runtime.h>

#define N_ 16
#define C_ 128
#define H_ 56
#define W_ 56
#define HW_ 3136

typedef __bf16 bf16x8 __attribute__((ext_vector_type(8)));
typedef __bf16 bf16x2 __attribute__((ext_vector_type(2)));
typedef float f32x4 __attribute__((ext_vector_type(4)));

#define XT_PER_N 401408   // 128*3136 (transposed x, bf16, [c][w][h])
#define T2_PLANE 3472     // 62*56 per channel (h-padded t2, bf16)
#define T2_PER_N 444416   // 128*3472
#define S_PER_N 114688    // 128*896
#define T10_PER_N 401408  // 128*3136

// workspace byte offsets (proven layout)
#define WS_T10_OFF   3670016u
#define WS_T3_OFF    12845056u
#define WS_T2PB_OFF  20185088u
#define WS_W2B_OFF   34406400u  // 98304 B, end 34504704

// ---------------------------------------------------------------------------
// F0 (fused prep): blocks [0,2048): p1 transpose (+ zero t2pb pad rows for
// the same (n,c) plane); blocks [2048,2240): w2b pack.
// ---------------------------------------------------------------------------
__global__ __launch_bounds__(256) void f0_prep(const float* __restrict__ x,
                                               const float* __restrict__ w2,
                                               __bf16* __restrict__ xT,
                                               __bf16* __restrict__ w2b,
                                               __bf16* __restrict__ t2pb) {
    int bid = blockIdx.x;
    int tid = threadIdx.x;
    if (bid < 2048) {
        int c = bid & 127, n = bid >> 7;
        __shared__ float xs[56 * 57];
        const float* xp = x + (size_t)(n * C_ + c) * HW_;
        for (int i = tid; i < HW_; i += 256) {
            int h = i / 56, w = i - 56 * h;
            xs[w * 57 + h] = xp[i];
        }
        __syncthreads();
        __bf16* op = xT + (size_t)(n * C_ + c) * HW_;
        for (int i = tid; i < 1568; i += 256) {
            int j = 2 * i;
            int wp = j / 56, h = j - 56 * wp;
            bf16x2 pr = {(__bf16)xs[wp * 57 + h], (__bf16)xs[wp * 57 + h + 1]};
            *(bf16x2*)&op[j] = pr;
        }
        // zero the 6 pad rows (h 0..2, 59..61) of t2pb plane (n,c)
        __bf16* tp = t2pb + (size_t)(n * C_ + c) * T2_PLANE;
        for (int i = tid; i < 336; i += 256)
            tp[(i < 168) ? i : (3136 + i)] = (__bf16)0.f;
    } else {
        int idx = (bid - 2048) * 256 + tid;  // < 49152
        int co = idx / 384, kk = idx - co * 384;
        int j = kk >> 7, ci = kk & 127;
        w2b[idx] = (__bf16)w2[co * 384 + ci * 3 + j];
    }
}

// ---------------------------------------------------------------------------
// F1 (fused main): blocks [0,448): K2 corr-GEMM; blocks [448,1344): K1 conv.
// K1 and K2 are data-independent -> co-resident waves hide each other's
// latency (r4 ran them serially at <22% occupancy each).
// ---------------------------------------------------------------------------
__global__ __launch_bounds__(256) void f1_main(const float* __restrict__ x,
                                               const __bf16* __restrict__ w2b,
                                               const __bf16* __restrict__ xT,
                                               __bf16* __restrict__ t2pb,
                                               float* __restrict__ t3) {
    __shared__ __align__(16) char smem[36864];
    int bid = blockIdx.x;
    int tid = threadIdx.x;
    int wv = tid >> 6, lane = tid & 63;
    int lm = lane & 15, lq = lane >> 4;
    int wi = wv >> 1, wj = wv & 1;

    if (bid < 448) {
        // ---------------- K2: t3[n,k,a,b] over linear j-window ----------------
        int hc = bid & 3;
        int k = (bid >> 2) % 7;
        int n = bid / 28;
        int w_lo = 6 - 2 * k; if (w_lo < 0) w_lo = 0;
        int w_hi = 62 - 2 * k; if (w_hi > 56) w_hi = 56;
        int jlo = w_lo * 56;
        int L = (w_hi - w_lo) * 56;   // 2800..3136, mult of 16
        int T = (L + 63) >> 6;
        int shiftA = (2 * k - 6) * 56;

        __bf16* As = (__bf16*)smem;             // 128*72
        __bf16* Bs = (__bf16*)(smem + 18432);   // 128*72

        f32x4 acc[4][4];
        f32x4 zero4 = {0.f, 0.f, 0.f, 0.f};
#pragma unroll
        for (int i = 0; i < 4; i++)
#pragma unroll
            for (int j = 0; j < 4; j++) acc[i][j] = zero4;

        const __bf16* Ag = xT + (size_t)n * XT_PER_N + jlo + shiftA;
        const __bf16* Bg = xT + (size_t)n * XT_PER_N + jlo;
        __bf16 bz = (__bf16)0.f;
        bf16x8 vzero = {bz, bz, bz, bz, bz, bz, bz, bz};

        for (int c = hc; c < T; c += 4) {
            int off0 = c * 64;
#pragma unroll
            for (int u = 0; u < 4; u++) {
                int v = tid + u * 256;       // [0,1024)
                int m = v & 7, a = v >> 3;
                int jo = off0 + 8 * m;
                bool val = (jo + 8 <= L);
                bf16x8 va = val ? *(const bf16x8*)(Ag + (size_t)a * HW_ + jo) : vzero;
                bf16x8 vb = val ? *(const bf16x8*)(Bg + (size_t)a * HW_ + jo) : vzero;
                *(bf16x8*)&As[a * 72 + 8 * m] = va;
                *(bf16x8*)&Bs[a * 72 + 8 * m] = vb;
            }
            __syncthreads();
#pragma unroll
            for (int kb = 0; kb < 2; kb++) {
                bf16x8 av[4], bv[4];
#pragma unroll
                for (int i = 0; i < 4; i++)
                    av[i] = *(const bf16x8*)&As[(wi * 64 + i * 16 + lm) * 72 + kb * 32 + lq * 8];
#pragma unroll
                for (int j = 0; j < 4; j++)
                    bv[j] = *(const bf16x8*)&Bs[(wj * 64 + j * 16 + lm) * 72 + kb * 32 + lq * 8];
#pragma unroll
                for (int i = 0; i < 4; i++)
#pragma unroll
                    for (int j = 0; j < 4; j++)
                        acc[i][j] = __builtin_amdgcn_mfma_f32_16x16x32_bf16(av[i], bv[j], acc[i][j], 0, 0, 0);
            }
            __syncthreads();
        }

        float* t3p = t3 + (size_t)(n * 7 + k) * (C_ * C_);
        const float inv56 = 1.0f / 56.0f;
#pragma unroll
        for (int i = 0; i < 4; i++)
#pragma unroll
            for (int j = 0; j < 4; j++)
#pragma unroll
                for (int r = 0; r < 4; r++) {
                    int a = wi * 64 + i * 16 + lq * 4 + r;
                    int b = wj * 64 + j * 16 + lm;
                    atomicAdd(&t3p[a * C_ + b], acc[i][j][r] * inv56);
                }
    } else {
        // ---------------- K1: dense 1x3 conv as MFMA GEMM ----------------
        int idx = bid - 448;
        int h = idx % 56, n = idx / 56;
        __bf16* Bs = (__bf16*)smem;            // 66*136 = 17952 B
        float* kbuf = (float*)(smem + 17952);  // 32*65*4 = 8320 B

        const float* xn = x + (size_t)n * C_ * HW_ + h * 56;
        for (int i = tid; i < 66 * 128; i += 256) {
            int ci = i / 66, wp = i - 66 * ci;
            int wx = wp - 1;
            float v = (wx >= 0 && wx < 56) ? xn[ci * HW_ + wx] : 0.f;
            Bs[wp * 136 + ci] = (__bf16)v;
        }

        f32x4 acc[4][2];
        f32x4 zero4 = {0.f, 0.f, 0.f, 0.f};
#pragma unroll
        for (int i = 0; i < 4; i++)
#pragma unroll
            for (int j = 0; j < 2; j++) acc[i][j] = zero4;

        // As chunk buffer lives in kbuf region? No: stage w2b chunks via LDS
        // region after Bs (reuse kbuf bytes for As chunks; both fit: As chunk
        // is 128*72... too big). Instead: r4 pattern with dedicated As region
        // is replaced by direct chunk staging into kbuf-adjacent area — keep
        // r4 semantics using the 18432 B after Bs (17952+18432=36384 <= 36864).
        __bf16* Asc = (__bf16*)(smem + 17952);  // 128*72 bf16 = 18432 B
        __syncthreads();

        for (int c6 = 0; c6 < 6; c6++) {
#pragma unroll
            for (int u = 0; u < 4; u++) {
                int v = tid + u * 256;
                int m = v & 7, co = v >> 3;
                *(bf16x8*)&Asc[co * 72 + 8 * m] =
                    *(const bf16x8*)(w2b + co * 384 + c6 * 64 + 8 * m);
            }
            __syncthreads();
#pragma unroll
            for (int kl = 0; kl < 2; kl++) {
                int ks = c6 * 2 + kl;        // k-step 0..11
                int j = ks >> 2;             // tap 0..2
                int cbase = (ks & 3) * 32;   // ci block base
                bf16x8 av[4], bv[2];
#pragma unroll
                for (int i = 0; i < 4; i++)
                    av[i] = *(const bf16x8*)&Asc[(wi * 64 + i * 16 + lm) * 72 + kl * 32 + lq * 8];
#pragma unroll
                for (int jt = 0; jt < 2; jt++) {
                    int row = wj * 32 + jt * 16 + lm + j;
                    bv[jt] = *(const bf16x8*)&Bs[row * 136 + cbase + lq * 8];
                }
#pragma unroll
                for (int i = 0; i < 4; i++)
#pragma unroll
                    for (int jt = 0; jt < 2; jt++)
                        acc[i][jt] = __builtin_amdgcn_mfma_f32_16x16x32_bf16(av[i], bv[jt], acc[i][jt], 0, 0, 0);
            }
            __syncthreads();
        }

        // store via LDS transpose: 4 chunks of 32 co-rows x 64 w
        __bf16* t2n = t2pb + (size_t)n * T2_PER_N;
#pragma unroll 1
        for (int i = 0; i < 4; i++) {
            __syncthreads();
#pragma unroll
            for (int jt = 0; jt < 2; jt++)
#pragma unroll
                for (int r = 0; r < 4; r++)
                    kbuf[(wi * 16 + lq * 4 + r) * 65 + wj * 32 + jt * 16 + lm] = acc[i][jt][r];
            __syncthreads();
            int row = tid >> 3, seg = tid & 7;
            if (seg < 7) {
                int co = (row < 16) ? (i * 16 + row) : (64 + i * 16 + (row - 16));
                const float* src = &kbuf[row * 65 + seg * 8];
                bf16x8 o8;
#pragma unroll
                for (int d = 0; d < 8; d++) o8[d] = (__bf16)src[d];
                *(bf16x8*)(t2n + (size_t)co * T2_PLANE + (h + 3) * 56 + seg * 8) = o8;
            }
        }
    }
}

// ---------------------------------------------------------------------------
// s-prep: s[n][b][ak] = bf16( t3[n][k][a][b] * p6w[a][k] * p9w[k][b] / sqrt(896) )
// ---------------------------------------------------------------------------
__global__ __launch_bounds__(256) void sprep(const float* __restrict__ t3,
                                             const float* __restrict__ p6w,
                                             const float* __restrict__ p9w,
                                             __bf16* __restrict__ s) {
    int idx = blockIdx.x * 256 + threadIdx.x;  // < 16*128*896
    int n = idx / S_PER_N;
    int rem = idx - n * S_PER_N;
    int b = rem / 896;
    int ak = rem - b * 896;
    int a = ak / 7, k = ak - 7 * a;
    const float rs = 0.03340766f;  // 1/sqrt(896)
    float v = t3[((size_t)(n * 7 + k) * C_ + a) * C_ + b] * p6w[a * 7 + k] *
              p9w[k * C_ + b] * rs;
    s[idx] = (__bf16)v;
}

// ---------------------------------------------------------------------------
// K3 (r4-proven): t10[n][b][hw] = sum_ak s[b][ak] * t2pb_lin[a*3472+hw+56k]
// Tile 128(b) x 64(hw), grid (49, N_). bf16 output via LDS transpose.
// ---------------------------------------------------------------------------
__global__ __launch_bounds__(256) void k3_mfma(const __bf16* __restrict__ s,
                                               const __bf16* __restrict__ t2pb,
                                               __bf16* __restrict__ t10) {
    int tile = blockIdx.x;  // 0..48
    int n = blockIdx.y;
    int hw0 = tile * 64;
    __shared__ __align__(16) __bf16 As[128 * 72];
    __shared__ __align__(16) __bf16 Bs[64 * 72];
    int tid = threadIdx.x;
    int wv = tid >> 6, lane = tid & 63;
    int lm = lane & 15, lq = lane >> 4;
    int wi = wv >> 1, wj = wv & 1;

    f32x4 acc[4][2];
    f32x4 zero4 = {0.f, 0.f, 0.f, 0.f};
#pragma unroll
    for (int i = 0; i < 4; i++)
#pragma unroll
        for (int j = 0; j < 2; j++) acc[i][j] = zero4;

    const __bf16* s_n = s + (size_t)n * S_PER_N;
    const __bf16* t2n = t2pb + (size_t)n * T2_PER_N;

    for (int kb = 0; kb < 14; kb++) {
#pragma unroll
        for (int u = 0; u < 4; u++) {
            int v = tid + u * 256;
            int m = v & 7, b = v >> 3;
            *(bf16x8*)&As[b * 72 + 8 * m] =
                *(const bf16x8*)(s_n + b * 896 + kb * 64 + 8 * m);
        }
        {
            int o = tid & 7;   // hw octet
            int p = tid >> 3;  // ak pair, [0,32)
            int ak0 = kb * 64 + 2 * p;
            int a0 = ak0 / 7, k0 = ak0 - 7 * a0;
            int ak1 = ak0 + 1;
            int a1 = ak1 / 7, k1 = ak1 - 7 * a1;
            int hwg = hw0 + 8 * o;
            bf16x8 v0 = *(const bf16x8*)(t2n + a0 * T2_PLANE + hwg + 56 * k0);
            bf16x8 v1 = *(const bf16x8*)(t2n + a1 * T2_PLANE + hwg + 56 * k1);
            int g = p >> 2;
            int off = (2 * p) & 7;
            int phys = ((g ^ o) << 3) + off;
#pragma unroll
            for (int j = 0; j < 8; j++) {
                int row = 8 * o + j;
                bf16x2 pr = {v0[j], v1[j]};
                *(bf16x2*)&Bs[row * 72 + phys] = pr;
            }
        }
        __syncthreads();
#pragma unroll
        for (int kbi = 0; kbi < 2; kbi++) {
            bf16x8 av[4], bv[2];
#pragma unroll
            for (int i = 0; i < 4; i++)
                av[i] = *(const bf16x8*)&As[(wi * 64 + i * 16 + lm) * 72 + kbi * 32 + lq * 8];
#pragma unroll
            for (int j = 0; j < 2; j++) {
                int row = wj * 32 + j * 16 + lm;
                int g = kbi * 4 + lq;
                int pg = g ^ (row >> 3);
                bv[j] = *(const bf16x8*)&Bs[row * 72 + pg * 8];
            }
#pragma unroll
            for (int i = 0; i < 4; i++)
#pragma unroll
                for (int j = 0; j < 2; j++)
                    acc[i][j] = __builtin_amdgcn_mfma_f32_16x16x32_bf16(av[i], bv[j], acc[i][j], 0, 0, 0);
        }
        __syncthreads();
    }

    float* buf = (float*)As;
    __bf16* t10n = t10 + (size_t)n * T10_PER_N;
#pragma unroll 1
    for (int i = 0; i < 4; i++) {
        __syncthreads();
#pragma unroll
        for (int j = 0; j < 2; j++)
#pragma unroll
            for (int r = 0; r < 4; r++)
                buf[(wi * 16 + lq * 4 + r) * 65 + wj * 32 + j * 16 + lm] = acc[i][j][r];
        __syncthreads();
        int row = tid >> 3, seg = tid & 7;
        int b = (row < 16) ? (i * 16 + row) : (64 + i * 16 + (row - 16));
        const float* src = &buf[row * 65 + seg * 8];
        bf16x8 o8;
#pragma unroll
        for (int d = 0; d < 8; d++) o8[d] = (__bf16)src[d];
        *(bf16x8*)(t10n + (size_t)b * HW_ + hw0 + seg * 8) = o8;
    }
}

// ---------------------------------------------------------------------------
// D: out = t8 - t10 + t7, one block per (n,b) plane.
// ---------------------------------------------------------------------------
__global__ __launch_bounds__(256) void d_final(const float* __restrict__ x,
                                               const __bf16* __restrict__ t2pb,
                                               const __bf16* __restrict__ t10,
                                               const float* __restrict__ w7,
                                               const float* __restrict__ w8,
                                               float* __restrict__ out) {
    int b = blockIdx.x, n = blockIdx.y;
    __shared__ float xs[64 * 65];
    __shared__ float t2s[56 * 60];
    int tid = threadIdx.x;
    const float* xp = x + (size_t)(n * C_ + b) * HW_;
    for (int i = tid; i < 64 * 65; i += 256) {
        int hh = i / 65, ww = i - 65 * hh;
        int h = hh - 4, w = ww - 4;
        float v = (h >= 0 && h < 56 && w >= 0 && w < 56) ? xp[h * 56 + w] : 0.f;
        xs[i] = v;
    }
    const __bf16* t2p = t2pb + (size_t)(n * C_ + b) * T2_PLANE;
    for (int i = tid; i < 56 * 60; i += 256) {
        int h = i / 60, ww = i - 60 * h;
        int w = ww - 2;
        float v = (w >= 0 && w < 56) ? (float)t2p[(h + 3) * 56 + w] : 0.f;
        t2s[i] = v;
    }
    __syncthreads();

    int r = tid >> 2;
    if (r >= 56) return;
    int w0 = (tid & 3) * 14;

    float w7r[5], w8r[25];
#pragma unroll
    for (int q = 0; q < 5; q++) w7r[q] = w7[b * 5 + q];
#pragma unroll
    for (int q = 0; q < 25; q++) w8r[q] = w8[b * 25 + q];

    float acc[14];
    {
        float tw[18];
#pragma unroll
        for (int c = 0; c < 18; c++) tw[c] = t2s[r * 60 + w0 + c];
#pragma unroll
        for (int i = 0; i < 14; i++)
            acc[i] = tw[i] * w7r[0] + tw[i + 1] * w7r[1] + tw[i + 2] * w7r[2] +
                     tw[i + 3] * w7r[3] + tw[i + 4] * w7r[4];
    }
#pragma unroll
    for (int p = 0; p < 5; p++) {
        float xv[22];
        int base = (r + 2 * p) * 65 + w0;
#pragma unroll
        for (int c = 0; c < 22; c++) xv[c] = xs[base + c];
#pragma unroll
        for (int i = 0; i < 14; i++)
            acc[i] += xv[i] * w8r[p * 5 + 0] + xv[i + 2] * w8r[p * 5 + 1] +
                      xv[i + 4] * w8r[p * 5 + 2] + xv[i + 6] * w8r[p * 5 + 3] +
                      xv[i + 8] * w8r[p * 5 + 4];
    }
    const __bf16* t10r = t10 + (size_t)(n * C_ + b) * HW_ + r * 56 + w0;
    float* outr = out + (size_t)(n * C_ + b) * HW_ + r * 56 + w0;
#pragma unroll
    for (int i = 0; i < 14; i++) outr[i] = acc[i] - (float)t10r[i];
}

extern "C" void kernel_launch(void* const* d_in, const int* in_sizes, int n_in,
                              void* d_out, int out_size, void* d_ws, size_t ws_size,
                              hipStream_t stream) {
    const float* x = (const float*)d_in[0];
    const float* w2 = (const float*)d_in[1];
    const float* p6w = (const float*)d_in[2];
    const float* w7 = (const float*)d_in[3];
    const float* w8 = (const float*)d_in[4];
    const float* p9w = (const float*)d_in[5];
    float* outp = (float*)d_out;

    char* ws = (char*)d_ws;
    __bf16* xT = (__bf16*)ws;
    __bf16* s = (__bf16*)ws;                     // overlay (xT dead after f1)
    __bf16* t10 = (__bf16*)(ws + WS_T10_OFF);    // overlays xT tail + t3 head
    float* t3 = (float*)(ws + WS_T3_OFF);
    __bf16* t2pb = (__bf16*)(ws + WS_T2PB_OFF);
    __bf16* w2b = (__bf16*)(ws + WS_W2B_OFF);

    hipMemsetAsync(t3, 0, (size_t)N_ * 7 * C_ * C_ * sizeof(float), stream);

    f0_prep<<<dim3(2240), 256, 0, stream>>>(x, w2, xT, w2b, t2pb);
    f1_main<<<dim3(1344), 256, 0, stream>>>(x, w2b, xT, t2pb, t3);
    sprep<<<dim3((N_ * S_PER_N) / 256), 256, 0, stream>>>(t3, p6w, p9w, s);
    k3_mfma<<<dim3(49, N_), 256, 0, stream>>>(s, t2pb, t10);
    d_final<<<dim3(C_, N_), 256, 0, stream>>>(x, t2pb, t10, w7, w8, outp);
}

// Round 7
// 210.150 us; speedup vs baseline: 1.4229x; 1.0525x over previous
//
#include <hip/hip_runtime.h>

#define N_ 16
#define C_ 128
#define H_ 56
#define W_ 56
#define HW_ 3136

typedef __bf16 bf16x8 __attribute__((ext_vector_type(8)));
typedef __bf16 bf16x2 __attribute__((ext_vector_type(2)));
typedef float f32x4 __attribute__((ext_vector_type(4)));

#define XT_PER_N 401408   // 128*3136 (transposed x, bf16, [c][w][h])
#define T2_PLANE 3472     // 62*56 per channel (h-padded t2, bf16)
#define T2_PER_N 444416   // 128*3472
#define S_PER_N 114688    // 128*896
#define T10_PER_N 401408  // 128*3136

// workspace byte offsets (proven layout; t3 now 4 k-slices = 4MB)
#define WS_T10_OFF   3670016u
#define WS_T3_OFF    12845056u
#define WS_T2PB_OFF  20185088u
#define WS_W2B_OFF   34406400u  // 98304 B, end 34504704

// ---------------------------------------------------------------------------
// F0 (fused prep): [0,2048): p1 transpose + zero t2pb pad rows;
// [2048,2240): w2b pack; [2240,2496): zero t3 (4MB).
// ---------------------------------------------------------------------------
__global__ __launch_bounds__(256) void f0_prep(const float* __restrict__ x,
                                               const float* __restrict__ w2,
                                               __bf16* __restrict__ xT,
                                               __bf16* __restrict__ w2b,
                                               __bf16* __restrict__ t2pb,
                                               float* __restrict__ t3) {
    int bid = blockIdx.x;
    int tid = threadIdx.x;
    if (bid < 2048) {
        int c = bid & 127, n = bid >> 7;
        __shared__ float xs[56 * 57];
        const float* xp = x + (size_t)(n * C_ + c) * HW_;
        for (int i = tid; i < HW_; i += 256) {
            int h = i / 56, w = i - 56 * h;
            xs[w * 57 + h] = xp[i];
        }
        __syncthreads();
        __bf16* op = xT + (size_t)(n * C_ + c) * HW_;
        for (int i = tid; i < 1568; i += 256) {
            int j = 2 * i;
            int wp = j / 56, h = j - 56 * wp;
            bf16x2 pr = {(__bf16)xs[wp * 57 + h], (__bf16)xs[wp * 57 + h + 1]};
            *(bf16x2*)&op[j] = pr;
        }
        __bf16* tp = t2pb + (size_t)(n * C_ + c) * T2_PLANE;
        for (int i = tid; i < 336; i += 256)
            tp[(i < 168) ? i : (3136 + i)] = (__bf16)0.f;
    } else if (bid < 2240) {
        int idx = (bid - 2048) * 256 + tid;  // < 49152
        int co = idx / 384, kk = idx - co * 384;
        int j = kk >> 7, ci = kk & 127;
        w2b[idx] = (__bf16)w2[co * 384 + ci * 3 + j];
    } else {
        f32x4 z4 = {0.f, 0.f, 0.f, 0.f};
        f32x4* t4 = (f32x4*)t3;
        int base = (bid - 2240) * 1024;
#pragma unroll
        for (int q = 0; q < 4; q++) t4[base + q * 256 + tid] = z4;
    }
}

// ---------------------------------------------------------------------------
// F1 (fused main): [0,256): K2 corr-GEMM (k=0..3 only, symmetry);
// [256,1152): K1 conv. Both register-prefetch their global loads so the
// latency overlaps the MFMA phase instead of the barrier drain.
// ---------------------------------------------------------------------------
__global__ __launch_bounds__(256) void f1_main(const float* __restrict__ x,
                                               const __bf16* __restrict__ w2b,
                                               const __bf16* __restrict__ xT,
                                               __bf16* __restrict__ t2pb,
                                               float* __restrict__ t3) {
    __shared__ __align__(16) char smem[36864];
    int bid = blockIdx.x;
    int tid = threadIdx.x;
    int wv = tid >> 6, lane = tid & 63;
    int lm = lane & 15, lq = lane >> 4;
    int wi = wv >> 1, wj = wv & 1;

    if (bid < 256) {
        // ---- K2: t3[n,k,a,b] = sum_j xT[a][j] * xT[b][j+(6-2k)*56], k=0..3
        int hc = bid & 3;
        int k = (bid >> 2) & 3;
        int n = bid >> 4;
        int w_lo = 6 - 2 * k;                 // 6,4,2,0
        int L = (56 - w_lo) * 56;             // 2800..3136, mult of 16
        int T = (L + 63) >> 6;

        __bf16* As = (__bf16*)smem;             // 128*72
        __bf16* Bs = (__bf16*)(smem + 18432);   // 128*72

        f32x4 acc[4][4];
        f32x4 zero4 = {0.f, 0.f, 0.f, 0.f};
#pragma unroll
        for (int i = 0; i < 4; i++)
#pragma unroll
            for (int j = 0; j < 4; j++) acc[i][j] = zero4;

        // for k<=3: A-window starts at 0, B-window starts at w_lo*56
        const __bf16* Ag = xT + (size_t)n * XT_PER_N;
        const __bf16* Bg = Ag + w_lo * 56;
        __bf16 bz = (__bf16)0.f;
        bf16x8 vzero = {bz, bz, bz, bz, bz, bz, bz, bz};

        int m8 = tid & 7, abase = tid >> 3;
        bf16x8 pva[4], pvb[4];
        auto LOAD = [&](int c) {
            int jo = c * 64 + 8 * m8;
            bool val = (jo + 8 <= L);
#pragma unroll
            for (int u = 0; u < 4; u++) {
                int a = abase + u * 32;
                pva[u] = val ? *(const bf16x8*)(Ag + (size_t)a * HW_ + jo) : vzero;
                pvb[u] = val ? *(const bf16x8*)(Bg + (size_t)a * HW_ + jo) : vzero;
            }
        };

        LOAD(hc);
        for (int c = hc; c < T; c += 4) {
#pragma unroll
            for (int u = 0; u < 4; u++) {
                int a = abase + u * 32;
                *(bf16x8*)&As[a * 72 + 8 * m8] = pva[u];
                *(bf16x8*)&Bs[a * 72 + 8 * m8] = pvb[u];
            }
            __syncthreads();
            if (c + 4 < T) LOAD(c + 4);
#pragma unroll
            for (int kb = 0; kb < 2; kb++) {
                bf16x8 av[4], bv[4];
#pragma unroll
                for (int i = 0; i < 4; i++)
                    av[i] = *(const bf16x8*)&As[(wi * 64 + i * 16 + lm) * 72 + kb * 32 + lq * 8];
#pragma unroll
                for (int j = 0; j < 4; j++)
                    bv[j] = *(const bf16x8*)&Bs[(wj * 64 + j * 16 + lm) * 72 + kb * 32 + lq * 8];
#pragma unroll
                for (int i = 0; i < 4; i++)
#pragma unroll
                    for (int j = 0; j < 4; j++)
                        acc[i][j] = __builtin_amdgcn_mfma_f32_16x16x32_bf16(av[i], bv[j], acc[i][j], 0, 0, 0);
            }
            __syncthreads();
        }

        float* t3p = t3 + (size_t)(n * 4 + k) * (C_ * C_);
        const float inv56 = 1.0f / 56.0f;
#pragma unroll
        for (int i = 0; i < 4; i++)
#pragma unroll
            for (int j = 0; j < 4; j++)
#pragma unroll
                for (int r = 0; r < 4; r++) {
                    int a = wi * 64 + i * 16 + lq * 4 + r;
                    int b = wj * 64 + j * 16 + lm;
                    atomicAdd(&t3p[a * C_ + b], acc[i][j][r] * inv56);
                }
    } else {
        // ---------------- K1: dense 1x3 conv as MFMA GEMM ----------------
        int idx = bid - 256;
        int h = idx % 56, n = idx / 56;
        __bf16* Bs = (__bf16*)smem;             // 66*136 = 17952 B
        __bf16* Asc = (__bf16*)(smem + 17952);  // 128*72 = 18432 B
        float* kbuf = (float*)(smem + 17952);   // epilogue reuse

        const float* xn = x + (size_t)n * C_ * HW_ + h * 56;
        for (int i = tid; i < 66 * 128; i += 256) {
            int ci = i / 66, wp = i - 66 * ci;
            int wx = wp - 1;
            float v = (wx >= 0 && wx < 56) ? xn[ci * HW_ + wx] : 0.f;
            Bs[wp * 136 + ci] = (__bf16)v;
        }

        f32x4 acc[4][2];
        f32x4 zero4 = {0.f, 0.f, 0.f, 0.f};
#pragma unroll
        for (int i = 0; i < 4; i++)
#pragma unroll
            for (int j = 0; j < 2; j++) acc[i][j] = zero4;

        int m8 = tid & 7, cobase = tid >> 3;
        bf16x8 pA[4];
        auto LOADA = [&](int c6) {
#pragma unroll
            for (int u = 0; u < 4; u++)
                pA[u] = *(const bf16x8*)(w2b + (cobase + u * 32) * 384 + c6 * 64 + 8 * m8);
        };

        LOADA(0);
        for (int c6 = 0; c6 < 6; c6++) {
#pragma unroll
            for (int u = 0; u < 4; u++)
                *(bf16x8*)&Asc[(cobase + u * 32) * 72 + 8 * m8] = pA[u];
            __syncthreads();
            if (c6 < 5) LOADA(c6 + 1);
#pragma unroll
            for (int kl = 0; kl < 2; kl++) {
                int ks = c6 * 2 + kl;        // k-step 0..11
                int j = ks >> 2;             // tap 0..2
                int cbase = (ks & 3) * 32;   // ci block base
                bf16x8 av[4], bv[2];
#pragma unroll
                for (int i = 0; i < 4; i++)
                    av[i] = *(const bf16x8*)&Asc[(wi * 64 + i * 16 + lm) * 72 + kl * 32 + lq * 8];
#pragma unroll
                for (int jt = 0; jt < 2; jt++) {
                    int row = wj * 32 + jt * 16 + lm + j;
                    bv[jt] = *(const bf16x8*)&Bs[row * 136 + cbase + lq * 8];
                }
#pragma unroll
                for (int i = 0; i < 4; i++)
#pragma unroll
                    for (int jt = 0; jt < 2; jt++)
                        acc[i][jt] = __builtin_amdgcn_mfma_f32_16x16x32_bf16(av[i], bv[jt], acc[i][jt], 0, 0, 0);
            }
            __syncthreads();
        }

        // store via LDS transpose: 4 chunks of 32 co-rows x 64 w
        __bf16* t2n = t2pb + (size_t)n * T2_PER_N;
#pragma unroll 1
        for (int i = 0; i < 4; i++) {
            __syncthreads();
#pragma unroll
            for (int jt = 0; jt < 2; jt++)
#pragma unroll
                for (int r = 0; r < 4; r++)
                    kbuf[(wi * 16 + lq * 4 + r) * 65 + wj * 32 + jt * 16 + lm] = acc[i][jt][r];
            __syncthreads();
            int row = tid >> 3, seg = tid & 7;
            if (seg < 7) {
                int co = (row < 16) ? (i * 16 + row) : (64 + i * 16 + (row - 16));
                const float* src = &kbuf[row * 65 + seg * 8];
                bf16x8 o8;
#pragma unroll
                for (int d = 0; d < 8; d++) o8[d] = (__bf16)src[d];
                *(bf16x8*)(t2n + (size_t)co * T2_PLANE + (h + 3) * 56 + seg * 8) = o8;
            }
        }
    }
}

// ---------------------------------------------------------------------------
// s-prep: s[n][b][ak] = bf16( t3v * p6w[a][k] * p9w[k][b] / sqrt(896) )
// t3 stored only for k=0..3; k>3 uses symmetry t3[k][a][b] = t3[6-k][b][a].
// ---------------------------------------------------------------------------
__global__ __launch_bounds__(256) void sprep(const float* __restrict__ t3,
                                             const float* __restrict__ p6w,
                                             const float* __restrict__ p9w,
                                             __bf16* __restrict__ s) {
    int idx = blockIdx.x * 256 + threadIdx.x;  // < 16*128*896
    int n = idx / S_PER_N;
    int rem = idx - n * S_PER_N;
    int b = rem / 896;
    int ak = rem - b * 896;
    int a = ak / 7, k = ak - 7 * a;
    const float rs = 0.03340766f;  // 1/sqrt(896)
    float t3v = (k <= 3)
                    ? t3[((size_t)(n * 4 + k) * C_ + a) * C_ + b]
                    : t3[((size_t)(n * 4 + (6 - k)) * C_ + b) * C_ + a];
    float v = t3v * p6w[a * 7 + k] * p9w[k * C_ + b] * rs;
    s[idx] = (__bf16)v;
}

// ---------------------------------------------------------------------------
// K3: t10[n][b][hw] = sum_ak s[b][ak] * t2pb_lin[a*3472+hw+56k]
// Register-prefetched staging (A direct-linear, B swizzled scatter).
// Tile 128(b) x 64(hw), grid (49, N_). bf16 output via LDS transpose.
// ---------------------------------------------------------------------------
__global__ __launch_bounds__(256) void k3_mfma(const __bf16* __restrict__ s,
                                               const __bf16* __restrict__ t2pb,
                                               __bf16* __restrict__ t10) {
    int tile = blockIdx.x;  // 0..48
    int n = blockIdx.y;
    int hw0 = tile * 64;
    __shared__ __align__(16) __bf16 As[128 * 72];
    __shared__ __align__(16) __bf16 Bs[64 * 72];
    int tid = threadIdx.x;
    int wv = tid >> 6, lane = tid & 63;
    int lm = lane & 15, lq = lane >> 4;
    int wi = wv >> 1, wj = wv & 1;

    f32x4 acc[4][2];
    f32x4 zero4 = {0.f, 0.f, 0.f, 0.f};
#pragma unroll
    for (int i = 0; i < 4; i++)
#pragma unroll
        for (int j = 0; j < 2; j++) acc[i][j] = zero4;

    const __bf16* s_n = s + (size_t)n * S_PER_N;
    const __bf16* t2n = t2pb + (size_t)n * T2_PER_N;

    int m8 = tid & 7, bbase = tid >> 3;
    int o = tid & 7;   // hw octet
    int p = tid >> 3;  // ak pair, [0,32)
    int g = p >> 2;
    int off = (2 * p) & 7;
    int phys = ((g ^ o) << 3) + off;

    bf16x8 pS[4], pB0, pB1;
    auto LOADC = [&](int kb) {
#pragma unroll
        for (int u = 0; u < 4; u++) {
            int b = bbase + u * 32;
            pS[u] = *(const bf16x8*)(s_n + b * 896 + kb * 64 + 8 * m8);
        }
        int ak0 = kb * 64 + 2 * p;
        int a0 = ak0 / 7, k0 = ak0 - 7 * a0;
        int ak1 = ak0 + 1;
        int a1 = ak1 / 7, k1 = ak1 - 7 * a1;
        int hwg = hw0 + 8 * o;
        pB0 = *(const bf16x8*)(t2n + a0 * T2_PLANE + hwg + 56 * k0);
        pB1 = *(const bf16x8*)(t2n + a1 * T2_PLANE + hwg + 56 * k1);
    };

    LOADC(0);
    for (int kb = 0; kb < 14; kb++) {
#pragma unroll
        for (int u = 0; u < 4; u++)
            *(bf16x8*)&As[(bbase + u * 32) * 72 + 8 * m8] = pS[u];
#pragma unroll
        for (int j = 0; j < 8; j++) {
            int row = 8 * o + j;
            bf16x2 pr = {pB0[j], pB1[j]};
            *(bf16x2*)&Bs[row * 72 + phys] = pr;
        }
        __syncthreads();
        if (kb < 13) LOADC(kb + 1);
#pragma unroll
        for (int kbi = 0; kbi < 2; kbi++) {
            bf16x8 av[4], bv[2];
#pragma unroll
            for (int i = 0; i < 4; i++)
                av[i] = *(const bf16x8*)&As[(wi * 64 + i * 16 + lm) * 72 + kbi * 32 + lq * 8];
#pragma unroll
            for (int j = 0; j < 2; j++) {
                int row = wj * 32 + j * 16 + lm;
                int gg = kbi * 4 + lq;
                int pg = gg ^ (row >> 3);
                bv[j] = *(const bf16x8*)&Bs[row * 72 + pg * 8];
            }
#pragma unroll
            for (int i = 0; i < 4; i++)
#pragma unroll
                for (int j = 0; j < 2; j++)
                    acc[i][j] = __builtin_amdgcn_mfma_f32_16x16x32_bf16(av[i], bv[j], acc[i][j], 0, 0, 0);
        }
        __syncthreads();
    }

    float* buf = (float*)As;
    __bf16* t10n = t10 + (size_t)n * T10_PER_N;
#pragma unroll 1
    for (int i = 0; i < 4; i++) {
        __syncthreads();
#pragma unroll
        for (int j = 0; j < 2; j++)
#pragma unroll
            for (int r = 0; r < 4; r++)
                buf[(wi * 16 + lq * 4 + r) * 65 + wj * 32 + j * 16 + lm] = acc[i][j][r];
        __syncthreads();
        int row = tid >> 3, seg = tid & 7;
        int b = (row < 16) ? (i * 16 + row) : (64 + i * 16 + (row - 16));
        const float* src = &buf[row * 65 + seg * 8];
        bf16x8 o8;
#pragma unroll
        for (int d = 0; d < 8; d++) o8[d] = (__bf16)src[d];
        *(bf16x8*)(t10n + (size_t)b * HW_ + hw0 + seg * 8) = o8;
    }
}

// ---------------------------------------------------------------------------
// D: out = t8 - t10 + t7, one block per (n,b) plane.
// ---------------------------------------------------------------------------
__global__ __launch_bounds__(256) void d_final(const float* __restrict__ x,
                                               const __bf16* __restrict__ t2pb,
                                               const __bf16* __restrict__ t10,
                                               const float* __restrict__ w7,
                                               const float* __restrict__ w8,
                                               float* __restrict__ out) {
    int b = blockIdx.x, n = blockIdx.y;
    __shared__ float xs[64 * 65];
    __shared__ float t2s[56 * 60];
    int tid = threadIdx.x;
    const float* xp = x + (size_t)(n * C_ + b) * HW_;
    for (int i = tid; i < 64 * 65; i += 256) {
        int hh = i / 65, ww = i - 65 * hh;
        int h = hh - 4, w = ww - 4;
        float v = (h >= 0 && h < 56 && w >= 0 && w < 56) ? xp[h * 56 + w] : 0.f;
        xs[i] = v;
    }
    const __bf16* t2p = t2pb + (size_t)(n * C_ + b) * T2_PLANE;
    for (int i = tid; i < 56 * 60; i += 256) {
        int h = i / 60, ww = i - 60 * h;
        int w = ww - 2;
        float v = (w >= 0 && w < 56) ? (float)t2p[(h + 3) * 56 + w] : 0.f;
        t2s[i] = v;
    }
    __syncthreads();

    int r = tid >> 2;
    if (r >= 56) return;
    int w0 = (tid & 3) * 14;

    float w7r[5], w8r[25];
#pragma unroll
    for (int q = 0; q < 5; q++) w7r[q] = w7[b * 5 + q];
#pragma unroll
    for (int q = 0; q < 25; q++) w8r[q] = w8[b * 25 + q];

    float acc[14];
    {
        float tw[18];
#pragma unroll
        for (int c = 0; c < 18; c++) tw[c] = t2s[r * 60 + w0 + c];
#pragma unroll
        for (int i = 0; i < 14; i++)
            acc[i] = tw[i] * w7r[0] + tw[i + 1] * w7r[1] + tw[i + 2] * w7r[2] +
                     tw[i + 3] * w7r[3] + tw[i + 4] * w7r[4];
    }
#pragma unroll
    for (int p = 0; p < 5; p++) {
        float xv[22];
        int base = (r + 2 * p) * 65 + w0;
#pragma unroll
        for (int c = 0; c < 22; c++) xv[c] = xs[base + c];
#pragma unroll
        for (int i = 0; i < 14; i++)
            acc[i] += xv[i] * w8r[p * 5 + 0] + xv[i + 2] * w8r[p * 5 + 1] +
                      xv[i + 4] * w8r[p * 5 + 2] + xv[i + 6] * w8r[p * 5 + 3] +
                      xv[i + 8] * w8r[p * 5 + 4];
    }
    const __bf16* t10r = t10 + (size_t)(n * C_ + b) * HW_ + r * 56 + w0;
    float* outr = out + (size_t)(n * C_ + b) * HW_ + r * 56 + w0;
#pragma unroll
    for (int i = 0; i < 14; i++) outr[i] = acc[i] - (float)t10r[i];
}

extern "C" void kernel_launch(void* const* d_in, const int* in_sizes, int n_in,
                              void* d_out, int out_size, void* d_ws, size_t ws_size,
                              hipStream_t stream) {
    const float* x = (const float*)d_in[0];
    const float* w2 = (const float*)d_in[1];
    const float* p6w = (const float*)d_in[2];
    const float* w7 = (const float*)d_in[3];
    const float* w8 = (const float*)d_in[4];
    const float* p9w = (const float*)d_in[5];
    float* outp = (float*)d_out;

    char* ws = (char*)d_ws;
    __bf16* xT = (__bf16*)ws;
    __bf16* s = (__bf16*)ws;                     // overlay (xT dead after f1)
    __bf16* t10 = (__bf16*)(ws + WS_T10_OFF);    // overlays t3 (dead after sprep)
    float* t3 = (float*)(ws + WS_T3_OFF);        // 16*4*128*128 fp32 = 4MB
    __bf16* t2pb = (__bf16*)(ws + WS_T2PB_OFF);
    __bf16* w2b = (__bf16*)(ws + WS_W2B_OFF);

    f0_prep<<<dim3(2496), 256, 0, stream>>>(x, w2, xT, w2b, t2pb, t3);
    f1_main<<<dim3(1152), 256, 0, stream>>>(x, w2b, xT, t2pb, t3);
    sprep<<<dim3((N_ * S_PER_N) / 256), 256, 0, stream>>>(t3, p6w, p9w, s);
    k3_mfma<<<dim3(49, N_), 256, 0, stream>>>(s, t2pb, t10);
    d_final<<<dim3(C_, N_), 256, 0, stream>>>(x, t2pb, t10, w7, w8, outp);
}